// Round 1
// baseline (182.334 us; speedup 1.0000x reference)
//
#include <hip/hip_runtime.h>
#include <cstddef>

#define NPT 16384   // N
#define NB  4       // B
// C = 64, K = 16, O = 128

// ---------------------------------------------------------------------------
// K1: fused 1x1 conv + BN(eps=1e-5) + ReLU for q, k, v.
// out layout [B][N][64] so that gathers in K2 are coalesced 256B rows.
// grid (N/64, B), block 256. Register-tiled GEMM, M=192 (q|k|v), tile n=64.
// ---------------------------------------------------------------------------
__global__ __launch_bounds__(256) void k_qkv(
    const float* __restrict__ feat_in,
    const float* __restrict__ Wq, const float* __restrict__ Wk, const float* __restrict__ Wv,
    const float* __restrict__ Qg, const float* __restrict__ Qb, const float* __restrict__ Qm, const float* __restrict__ Qv,
    const float* __restrict__ Kg, const float* __restrict__ Kb, const float* __restrict__ Km, const float* __restrict__ Kv,
    const float* __restrict__ Vg, const float* __restrict__ Vb, const float* __restrict__ Vm, const float* __restrict__ Vv,
    float* __restrict__ qo, float* __restrict__ ko, float* __restrict__ vo)
{
    __shared__ float wt[64][192];   // wt[c][t*64+o] = W_t[o][c]   (48 KiB)
    __shared__ float fs[64][64];    // fs[c][n_local]              (16 KiB)
    const int tid = threadIdx.x;
    const int b   = blockIdx.y;
    const int n0  = blockIdx.x * 64;

    // ---- stage weights transposed (unscaled; BN folded in epilogue) ----
    {
        const int o  = tid >> 2;          // 0..63
        const int cb = (tid & 3) * 16;    // 0,16,32,48
        const float* Ws[3] = {Wq, Wk, Wv};
        #pragma unroll
        for (int t = 0; t < 3; ++t) {
            const float4* src = reinterpret_cast<const float4*>(Ws[t] + o * 64 + cb);
            #pragma unroll
            for (int k4 = 0; k4 < 4; ++k4) {
                float4 w4 = src[k4];
                wt[cb + k4 * 4 + 0][t * 64 + o] = w4.x;
                wt[cb + k4 * 4 + 1][t * 64 + o] = w4.y;
                wt[cb + k4 * 4 + 2][t * 64 + o] = w4.z;
                wt[cb + k4 * 4 + 3][t * 64 + o] = w4.w;
            }
        }
    }
    // ---- stage feature tile: fs[c][n] from feature[b][c][n0+n] ----
    #pragma unroll
    for (int i = 0; i < 16; ++i) {
        int flat = tid + i * 256;       // 4096 elements
        int c = flat >> 6, n = flat & 63;
        fs[c][n] = feat_in[((size_t)b * 64 + c) * NPT + n0 + n];
    }
    __syncthreads();

    const int to = tid & 15;   // o-quad
    const int tn = tid >> 4;   // n-quad
    float acc[3][4][4];
    #pragma unroll
    for (int t = 0; t < 3; ++t)
        #pragma unroll
        for (int i = 0; i < 4; ++i)
            #pragma unroll
            for (int j = 0; j < 4; ++j) acc[t][i][j] = 0.f;

    #pragma unroll 4
    for (int c = 0; c < 64; ++c) {
        float4 f4  = *reinterpret_cast<const float4*>(&fs[c][tn * 4]);
        float4 wq4 = *reinterpret_cast<const float4*>(&wt[c][to * 4]);
        float4 wk4 = *reinterpret_cast<const float4*>(&wt[c][64 + to * 4]);
        float4 wv4 = *reinterpret_cast<const float4*>(&wt[c][128 + to * 4]);
        float fr[4]    = {f4.x, f4.y, f4.z, f4.w};
        float wr[3][4] = {{wq4.x, wq4.y, wq4.z, wq4.w},
                          {wk4.x, wk4.y, wk4.z, wk4.w},
                          {wv4.x, wv4.y, wv4.z, wv4.w}};
        #pragma unroll
        for (int t = 0; t < 3; ++t)
            #pragma unroll
            for (int oi = 0; oi < 4; ++oi)
                #pragma unroll
                for (int nn = 0; nn < 4; ++nn)
                    acc[t][oi][nn] = fmaf(wr[t][oi], fr[nn], acc[t][oi][nn]);
    }

    // ---- epilogue: BN fold + ReLU + coalesced float4 stores ----
    const float* Gs[3] = {Qg, Kg, Vg};
    const float* Bs[3] = {Qb, Kb, Vb};
    const float* Ms[3] = {Qm, Km, Vm};
    const float* Vs[3] = {Qv, Kv, Vv};
    float* Os[3] = {qo, ko, vo};
    #pragma unroll
    for (int t = 0; t < 3; ++t) {
        float sc[4], sh[4];
        #pragma unroll
        for (int oi = 0; oi < 4; ++oi) {
            int o = to * 4 + oi;
            float s = Gs[t][o] * rsqrtf(Vs[t][o] + 1e-5f);
            sc[oi] = s;
            sh[oi] = Bs[t][o] - Ms[t][o] * s;
        }
        #pragma unroll
        for (int nn = 0; nn < 4; ++nn) {
            float4 r;
            r.x = fmaxf(fmaf(acc[t][0][nn], sc[0], sh[0]), 0.f);
            r.y = fmaxf(fmaf(acc[t][1][nn], sc[1], sh[1]), 0.f);
            r.z = fmaxf(fmaf(acc[t][2][nn], sc[2], sh[2]), 0.f);
            r.w = fmaxf(fmaf(acc[t][3][nn], sc[3], sh[3]), 0.f);
            *reinterpret_cast<float4*>(
                Os[t] + (((size_t)b * NPT + n0 + tn * 4 + nn) << 6) + to * 4) = r;
        }
    }
}

// ---------------------------------------------------------------------------
// K2: gather + attention + weighted sum. One wave per point, lane = channel.
// Reads q from qfeat, writes feat back to qfeat IN PLACE (each address is
// touched by exactly one lane: read-then-write, no cross-point use of q).
// grid = B*N/4 blocks of 256 threads (4 waves = 4 points per block).
// ---------------------------------------------------------------------------
__global__ __launch_bounds__(256) void k_attn(
    const float* __restrict__ xinfo,
    const int*   __restrict__ nidx,
    float*                    qfeat,      // q in, feat out (aliased on purpose)
    const float* __restrict__ kb,
    const float* __restrict__ vb)
{
    const int tid  = threadIdx.x;
    const int lane = tid & 63;
    const int p    = blockIdx.x * 4 + (tid >> 6);   // 0 .. B*N-1
    const int b    = p >> 14;
    const int n    = p & 16383;

    // neighbor indices: lanes 0..15 hold j=0..15 (16..63 replicate)
    int idxv = nidx[(p << 4) + (lane & 15)];

    float qc = qfeat[((size_t)p << 6) + lane];

    // x_info[b][c=lane][n][0..15]: 64B per lane, 4x float4
    const float4* xp = reinterpret_cast<const float4*>(
        xinfo + ((((size_t)b << 6) + lane) * NPT + n) * 16);
    float4 xa = xp[0], xb4 = xp[1], xc4 = xp[2], xd4 = xp[3];
    float x[16] = {xa.x, xa.y, xa.z, xa.w,  xb4.x, xb4.y, xb4.z, xb4.w,
                   xc4.x, xc4.y, xc4.z, xc4.w,  xd4.x, xd4.y, xd4.z, xd4.w};

    // gathers: per j, all 64 lanes read contiguous 256B row of k / v
    float kgv[16], vgv[16];
    #pragma unroll
    for (int j = 0; j < 16; ++j) {
        int nj = __shfl(idxv, j);
        size_t gb = (((size_t)((b << 14) | nj)) << 6) + lane;
        kgv[j] = kb[gb];
        vgv[j] = vb[gb];
    }

    float w[16];
    #pragma unroll
    for (int j = 0; j < 16; ++j) w[j] = x[j] * (kgv[j] - qc);

    float mx = w[0];
    #pragma unroll
    for (int j = 1; j < 16; ++j) mx = fmaxf(mx, w[j]);

    float es = 0.f, fsum = 0.f;
    #pragma unroll
    for (int j = 0; j < 16; ++j) {
        float e = __expf(w[j] - mx);
        es += e;
        fsum = fmaf(e, vgv[j], fsum);
    }

    qfeat[((size_t)p << 6) + lane] = fsum / es;   // feat, in place over q
}

// ---------------------------------------------------------------------------
// K3: mlp2 = 1x1 conv (O=128) + BN(eps=1e-6) + LeakyReLU(0.2).
// grid (N/64, B), block 256. Tile 128o x 64n; wt & feat transposed into LDS.
// Output [B][128][N]; stores coalesced along n (lanes tn = consecutive n).
// ---------------------------------------------------------------------------
__global__ __launch_bounds__(256) void k_mlp2(
    const float* __restrict__ feat,
    const float* __restrict__ m2w,
    const float* __restrict__ g2, const float* __restrict__ b2,
    const float* __restrict__ m2, const float* __restrict__ v2,
    float* __restrict__ out)
{
    __shared__ float wt [64][132];  // wt[c][o], padded (33 KiB)
    __shared__ float fsh[64][68];   // fsh[c][n], padded (17 KiB)
    const int tid = threadIdx.x;
    const int b   = blockIdx.y;
    const int n0  = blockIdx.x * 64;

    // ---- stage wt[c][o] from m2w[o][c] ----
    {
        const int o  = tid >> 1;          // 0..127
        const int ch = (tid & 1) * 32;    // 0 or 32
        const float4* src = reinterpret_cast<const float4*>(m2w + o * 64 + ch);
        #pragma unroll
        for (int k4 = 0; k4 < 8; ++k4) {
            float4 w4 = src[k4];
            wt[ch + k4 * 4 + 0][o] = w4.x;
            wt[ch + k4 * 4 + 1][o] = w4.y;
            wt[ch + k4 * 4 + 2][o] = w4.z;
            wt[ch + k4 * 4 + 3][o] = w4.w;
        }
    }
    // ---- stage fsh[c][n] from feat[b][n0+n][c] ----
    {
        const int c4 = tid & 15;       // float4 index along c
        const int nl = tid >> 4;       // 0..15
        #pragma unroll
        for (int i = 0; i < 4; ++i) {
            int n = nl + i * 16;
            float4 f4 = *reinterpret_cast<const float4*>(
                feat + (((size_t)b * NPT + n0 + n) << 6) + c4 * 4);
            fsh[c4 * 4 + 0][n] = f4.x;
            fsh[c4 * 4 + 1][n] = f4.y;
            fsh[c4 * 4 + 2][n] = f4.z;
            fsh[c4 * 4 + 3][n] = f4.w;
        }
    }
    __syncthreads();

    const int tn = tid & 15;   // lane's n offset (consecutive for coalesced stores)
    const int to = tid >> 4;   // 0..15 -> o quads {to*4..+3} and {64+to*4..+3}
    float acc[2][4][4];        // [half][oi][ni]
    #pragma unroll
    for (int h = 0; h < 2; ++h)
        #pragma unroll
        for (int i = 0; i < 4; ++i)
            #pragma unroll
            for (int j = 0; j < 4; ++j) acc[h][i][j] = 0.f;

    #pragma unroll 4
    for (int c = 0; c < 64; ++c) {
        float4 wa = *reinterpret_cast<const float4*>(&wt[c][to * 4]);
        float4 wb = *reinterpret_cast<const float4*>(&wt[c][64 + to * 4]);
        float wra[4] = {wa.x, wa.y, wa.z, wa.w};
        float wrb[4] = {wb.x, wb.y, wb.z, wb.w};
        float fr[4];
        #pragma unroll
        for (int ni = 0; ni < 4; ++ni) fr[ni] = fsh[c][ni * 16 + tn];
        #pragma unroll
        for (int oi = 0; oi < 4; ++oi)
            #pragma unroll
            for (int ni = 0; ni < 4; ++ni) {
                acc[0][oi][ni] = fmaf(wra[oi], fr[ni], acc[0][oi][ni]);
                acc[1][oi][ni] = fmaf(wrb[oi], fr[ni], acc[1][oi][ni]);
            }
    }

    #pragma unroll
    for (int h = 0; h < 2; ++h)
        #pragma unroll
        for (int oi = 0; oi < 4; ++oi) {
            int o = h * 64 + to * 4 + oi;
            float s  = g2[o] * rsqrtf(v2[o] + 1e-6f);
            float sh = b2[o] - m2[o] * s;
            #pragma unroll
            for (int ni = 0; ni < 4; ++ni) {
                float y = fmaf(acc[h][oi][ni], s, sh);
                y = (y >= 0.f) ? y : 0.2f * y;
                out[(((size_t)b << 7) + o) * NPT + n0 + ni * 16 + tn] = y;
            }
        }
}

// ---------------------------------------------------------------------------
extern "C" void kernel_launch(void* const* d_in, const int* in_sizes, int n_in,
                              void* d_out, int out_size, void* d_ws, size_t ws_size,
                              hipStream_t stream)
{
    const float* xinfo   = (const float*)d_in[0];
    const float* feature = (const float*)d_in[1];
    const int*   nidx    = (const int*)  d_in[2];
    const float* Wq = (const float*)d_in[3];
    const float* Qg = (const float*)d_in[4];
    const float* Qb = (const float*)d_in[5];
    const float* Qm = (const float*)d_in[6];
    const float* Qv = (const float*)d_in[7];
    const float* Wk = (const float*)d_in[8];
    const float* Kg = (const float*)d_in[9];
    const float* Kb = (const float*)d_in[10];
    const float* Km = (const float*)d_in[11];
    const float* Kv = (const float*)d_in[12];
    const float* Wv = (const float*)d_in[13];
    const float* Vg = (const float*)d_in[14];
    const float* Vb = (const float*)d_in[15];
    const float* Vm = (const float*)d_in[16];
    const float* Vv = (const float*)d_in[17];
    const float* m2w = (const float*)d_in[18];
    const float* g2  = (const float*)d_in[19];
    const float* b2  = (const float*)d_in[20];
    const float* m2  = (const float*)d_in[21];
    const float* v2  = (const float*)d_in[22];
    float* out = (float*)d_out;

    // workspace: q/feat (in-place), k, v  -- each B*N*64 floats = 16 MiB
    float* ws   = (float*)d_ws;
    float* qf   = ws;
    float* kbuf = ws + (size_t)NB * NPT * 64;
    float* vbuf = ws + (size_t)2 * NB * NPT * 64;

    k_qkv<<<dim3(NPT / 64, NB), 256, 0, stream>>>(
        feature, Wq, Wk, Wv,
        Qg, Qb, Qm, Qv, Kg, Kb, Km, Kv, Vg, Vb, Vm, Vv,
        qf, kbuf, vbuf);

    k_attn<<<(NB * NPT) / 4, 256, 0, stream>>>(xinfo, nidx, qf, kbuf, vbuf);

    k_mlp2<<<dim3(NPT / 64, NB), 256, 0, stream>>>(qf, m2w, g2, b2, m2, v2, out);
}

// Round 2
// 152.384 us; speedup vs baseline: 1.1965x; 1.1965x over previous
//
#include <hip/hip_runtime.h>
#include <cstddef>

#define NPT 16384   // N
#define NB  4       // B
// C = 64, K = 16, O = 128

// ---------------------------------------------------------------------------
// K1: fused 1x1 conv + BN(eps=1e-5) + ReLU for q, k, v.
// q out: [B][N][64]. k,v out INTERLEAVED: kv[p][c][2] = {k,v} so K2's gathers
// read one 512B-contiguous row per neighbor instead of two 256B rows.
// grid (N/64, B), block 256. Register-tiled GEMM, M=192 (q|k|v), tile n=64.
// ---------------------------------------------------------------------------
__global__ __launch_bounds__(256) void k_qkv(
    const float* __restrict__ feat_in,
    const float* __restrict__ Wq, const float* __restrict__ Wk, const float* __restrict__ Wv,
    const float* __restrict__ Qg, const float* __restrict__ Qb, const float* __restrict__ Qm, const float* __restrict__ Qv,
    const float* __restrict__ Kg, const float* __restrict__ Kb, const float* __restrict__ Km, const float* __restrict__ Kv,
    const float* __restrict__ Vg, const float* __restrict__ Vb, const float* __restrict__ Vm, const float* __restrict__ Vv,
    float* __restrict__ qo, float* __restrict__ kvo)
{
    __shared__ float wt[64][192];   // wt[c][t*64+o] = W_t[o][c]   (48 KiB)
    __shared__ float fs[64][64];    // fs[c][n_local]              (16 KiB)
    const int tid = threadIdx.x;
    const int b   = blockIdx.y;
    const int n0  = blockIdx.x * 64;

    // ---- stage weights transposed (unscaled; BN folded in epilogue) ----
    {
        const int o  = tid >> 2;          // 0..63
        const int cb = (tid & 3) * 16;    // 0,16,32,48
        const float* Ws[3] = {Wq, Wk, Wv};
        #pragma unroll
        for (int t = 0; t < 3; ++t) {
            const float4* src = reinterpret_cast<const float4*>(Ws[t] + o * 64 + cb);
            #pragma unroll
            for (int k4 = 0; k4 < 4; ++k4) {
                float4 w4 = src[k4];
                wt[cb + k4 * 4 + 0][t * 64 + o] = w4.x;
                wt[cb + k4 * 4 + 1][t * 64 + o] = w4.y;
                wt[cb + k4 * 4 + 2][t * 64 + o] = w4.z;
                wt[cb + k4 * 4 + 3][t * 64 + o] = w4.w;
            }
        }
    }
    // ---- stage feature tile: fs[c][n] from feature[b][c][n0+n] ----
    #pragma unroll
    for (int i = 0; i < 16; ++i) {
        int flat = tid + i * 256;       // 4096 elements
        int c = flat >> 6, n = flat & 63;
        fs[c][n] = feat_in[((size_t)b * 64 + c) * NPT + n0 + n];
    }
    __syncthreads();

    const int to = tid & 15;   // o-quad
    const int tn = tid >> 4;   // n-quad
    float acc[3][4][4];
    #pragma unroll
    for (int t = 0; t < 3; ++t)
        #pragma unroll
        for (int i = 0; i < 4; ++i)
            #pragma unroll
            for (int j = 0; j < 4; ++j) acc[t][i][j] = 0.f;

    #pragma unroll 4
    for (int c = 0; c < 64; ++c) {
        float4 f4  = *reinterpret_cast<const float4*>(&fs[c][tn * 4]);
        float4 wq4 = *reinterpret_cast<const float4*>(&wt[c][to * 4]);
        float4 wk4 = *reinterpret_cast<const float4*>(&wt[c][64 + to * 4]);
        float4 wv4 = *reinterpret_cast<const float4*>(&wt[c][128 + to * 4]);
        float fr[4]    = {f4.x, f4.y, f4.z, f4.w};
        float wr[3][4] = {{wq4.x, wq4.y, wq4.z, wq4.w},
                          {wk4.x, wk4.y, wk4.z, wk4.w},
                          {wv4.x, wv4.y, wv4.z, wv4.w}};
        #pragma unroll
        for (int t = 0; t < 3; ++t)
            #pragma unroll
            for (int oi = 0; oi < 4; ++oi)
                #pragma unroll
                for (int nn = 0; nn < 4; ++nn)
                    acc[t][oi][nn] = fmaf(wr[t][oi], fr[nn], acc[t][oi][nn]);
    }

    // ---- epilogue: BN fold + ReLU ----
    float scq[4], shq[4], sck[4], shk[4], scv[4], shv[4];
    #pragma unroll
    for (int oi = 0; oi < 4; ++oi) {
        int o = to * 4 + oi;
        float s;
        s = Qg[o] * rsqrtf(Qv[o] + 1e-5f); scq[oi] = s; shq[oi] = Qb[o] - Qm[o] * s;
        s = Kg[o] * rsqrtf(Kv[o] + 1e-5f); sck[oi] = s; shk[oi] = Kb[o] - Km[o] * s;
        s = Vg[o] * rsqrtf(Vv[o] + 1e-5f); scv[oi] = s; shv[oi] = Vb[o] - Vm[o] * s;
    }
    #pragma unroll
    for (int nn = 0; nn < 4; ++nn) {
        const size_t pidx = (size_t)b * NPT + n0 + tn * 4 + nn;
        // q: [p][c]
        float4 rq;
        rq.x = fmaxf(fmaf(acc[0][0][nn], scq[0], shq[0]), 0.f);
        rq.y = fmaxf(fmaf(acc[0][1][nn], scq[1], shq[1]), 0.f);
        rq.z = fmaxf(fmaf(acc[0][2][nn], scq[2], shq[2]), 0.f);
        rq.w = fmaxf(fmaf(acc[0][3][nn], scq[3], shq[3]), 0.f);
        *reinterpret_cast<float4*>(qo + (pidx << 6) + to * 4) = rq;
        // kv interleaved: [p][c][{k,v}]
        float rk[4], rv[4];
        #pragma unroll
        for (int oi = 0; oi < 4; ++oi) {
            rk[oi] = fmaxf(fmaf(acc[1][oi][nn], sck[oi], shk[oi]), 0.f);
            rv[oi] = fmaxf(fmaf(acc[2][oi][nn], scv[oi], shv[oi]), 0.f);
        }
        float* dst = kvo + (pidx << 7) + to * 8;
        *reinterpret_cast<float4*>(dst)     = make_float4(rk[0], rv[0], rk[1], rv[1]);
        *reinterpret_cast<float4*>(dst + 4) = make_float4(rk[2], rv[2], rk[3], rv[3]);
    }
}

// ---------------------------------------------------------------------------
// K2: gather + attention + weighted sum. One wave per point, lane = channel.
// x_info is staged through LDS with a COALESCED cooperative load: the block's
// 4-point tile is 64 contiguous floats per channel, so each wave-instruction
// covers 4 contiguous 256B segments instead of 64 scattered 16B requests.
// k/v gathers read the interleaved kv buffer: 512B contiguous per neighbor.
// Writes feat back over q IN PLACE (each address touched by exactly one lane).
// grid = B*N/4 blocks of 256 threads (4 waves = 4 points per block).
// ---------------------------------------------------------------------------
__global__ __launch_bounds__(256) void k_attn(
    const float* __restrict__ xinfo,
    const int*   __restrict__ nidx,
    float*                    qfeat,      // q in, feat out (aliased on purpose)
    const float* __restrict__ kv)
{
    __shared__ float xs[64][68];   // [c][pl*16+j], pad 4 -> <=2-way bank alias
    const int tid  = threadIdx.x;
    const int lane = tid & 63;
    const int wv   = tid >> 6;
    const int p0   = blockIdx.x * 4;
    const int b    = p0 >> 14;
    const int n0   = p0 & 16383;
    const int p    = p0 + wv;

    // idx first: the gathers depend on it
    int idxv = nidx[((size_t)p << 4) + (lane & 15)];
    float qc = qfeat[((size_t)p << 6) + lane];

    // ---- cooperative x_info tile load: 4096 floats = 4 x float4 / thread ----
    const float* xbase = xinfo + (((size_t)b * 64) * NPT + n0) * 16;
    float4 xr[4];
    #pragma unroll
    for (int i = 0; i < 4; ++i) {
        int f = tid + i * 256;        // float4 index in tile, 0..1023
        int c = f >> 4, s = f & 15;   // channel, 16B-segment within 256B run
        xr[i] = *reinterpret_cast<const float4*>(xbase + (size_t)c * (NPT * 16) + s * 4);
    }
    #pragma unroll
    for (int i = 0; i < 4; ++i) {
        int f = tid + i * 256;
        int c = f >> 4, s = f & 15;
        *reinterpret_cast<float4*>(&xs[c][s * 4]) = xr[i];
    }

    // ---- gathers: per j, 64 lanes read one contiguous 512B kv row ----
    float kgv[16], vgv[16];
    const float2* kv2 = reinterpret_cast<const float2*>(kv);
    #pragma unroll
    for (int j = 0; j < 16; ++j) {
        int nj = __shfl(idxv, j);
        float2 g = kv2[(((size_t)((b << 14) | nj)) << 6) + lane];
        kgv[j] = g.x; vgv[j] = g.y;
    }

    __syncthreads();

    // ---- softmax over K=16, fully in-lane ----
    float w[16];
    #pragma unroll
    for (int k4 = 0; k4 < 4; ++k4) {
        float4 x4 = *reinterpret_cast<const float4*>(&xs[lane][wv * 16 + k4 * 4]);
        w[k4 * 4 + 0] = x4.x * (kgv[k4 * 4 + 0] - qc);
        w[k4 * 4 + 1] = x4.y * (kgv[k4 * 4 + 1] - qc);
        w[k4 * 4 + 2] = x4.z * (kgv[k4 * 4 + 2] - qc);
        w[k4 * 4 + 3] = x4.w * (kgv[k4 * 4 + 3] - qc);
    }

    float mx = w[0];
    #pragma unroll
    for (int j = 1; j < 16; ++j) mx = fmaxf(mx, w[j]);

    float es = 0.f, fsum = 0.f;
    #pragma unroll
    for (int j = 0; j < 16; ++j) {
        float e = __expf(w[j] - mx);
        es += e;
        fsum = fmaf(e, vgv[j], fsum);
    }

    qfeat[((size_t)p << 6) + lane] = fsum / es;   // feat, in place over q
}

// ---------------------------------------------------------------------------
// K3: mlp2 = 1x1 conv (O=128) + BN(eps=1e-6) + LeakyReLU(0.2).
// grid (N/64, B), block 256. Tile 128o x 64n; wt & feat transposed into LDS.
// Output [B][128][N]; stores coalesced along n (lanes tn = consecutive n).
// ---------------------------------------------------------------------------
__global__ __launch_bounds__(256) void k_mlp2(
    const float* __restrict__ feat,
    const float* __restrict__ m2w,
    const float* __restrict__ g2, const float* __restrict__ b2,
    const float* __restrict__ m2, const float* __restrict__ v2,
    float* __restrict__ out)
{
    __shared__ float wt [64][132];  // wt[c][o], padded (33 KiB)
    __shared__ float fsh[64][68];   // fsh[c][n], padded (17 KiB)
    const int tid = threadIdx.x;
    const int b   = blockIdx.y;
    const int n0  = blockIdx.x * 64;

    // ---- stage wt[c][o] from m2w[o][c] ----
    {
        const int o  = tid >> 1;          // 0..127
        const int ch = (tid & 1) * 32;    // 0 or 32
        const float4* src = reinterpret_cast<const float4*>(m2w + o * 64 + ch);
        #pragma unroll
        for (int k4 = 0; k4 < 8; ++k4) {
            float4 w4 = src[k4];
            wt[ch + k4 * 4 + 0][o] = w4.x;
            wt[ch + k4 * 4 + 1][o] = w4.y;
            wt[ch + k4 * 4 + 2][o] = w4.z;
            wt[ch + k4 * 4 + 3][o] = w4.w;
        }
    }
    // ---- stage fsh[c][n] from feat[b][n0+n][c] ----
    {
        const int c4 = tid & 15;       // float4 index along c
        const int nl = tid >> 4;       // 0..15
        #pragma unroll
        for (int i = 0; i < 4; ++i) {
            int n = nl + i * 16;
            float4 f4 = *reinterpret_cast<const float4*>(
                feat + (((size_t)b * NPT + n0 + n) << 6) + c4 * 4);
            fsh[c4 * 4 + 0][n] = f4.x;
            fsh[c4 * 4 + 1][n] = f4.y;
            fsh[c4 * 4 + 2][n] = f4.z;
            fsh[c4 * 4 + 3][n] = f4.w;
        }
    }
    __syncthreads();

    const int tn = tid & 15;   // lane's n offset (consecutive for coalesced stores)
    const int to = tid >> 4;   // 0..15 -> o quads {to*4..+3} and {64+to*4..+3}
    float acc[2][4][4];        // [half][oi][ni]
    #pragma unroll
    for (int h = 0; h < 2; ++h)
        #pragma unroll
        for (int i = 0; i < 4; ++i)
            #pragma unroll
            for (int j = 0; j < 4; ++j) acc[h][i][j] = 0.f;

    #pragma unroll 4
    for (int c = 0; c < 64; ++c) {
        float4 wa = *reinterpret_cast<const float4*>(&wt[c][to * 4]);
        float4 wb = *reinterpret_cast<const float4*>(&wt[c][64 + to * 4]);
        float wra[4] = {wa.x, wa.y, wa.z, wa.w};
        float wrb[4] = {wb.x, wb.y, wb.z, wb.w};
        float fr[4];
        #pragma unroll
        for (int ni = 0; ni < 4; ++ni) fr[ni] = fsh[c][ni * 16 + tn];
        #pragma unroll
        for (int oi = 0; oi < 4; ++oi)
            #pragma unroll
            for (int ni = 0; ni < 4; ++ni) {
                acc[0][oi][ni] = fmaf(wra[oi], fr[ni], acc[0][oi][ni]);
                acc[1][oi][ni] = fmaf(wrb[oi], fr[ni], acc[1][oi][ni]);
            }
    }

    #pragma unroll
    for (int h = 0; h < 2; ++h)
        #pragma unroll
        for (int oi = 0; oi < 4; ++oi) {
            int o = h * 64 + to * 4 + oi;
            float s  = g2[o] * rsqrtf(v2[o] + 1e-6f);
            float sh = b2[o] - m2[o] * s;
            #pragma unroll
            for (int ni = 0; ni < 4; ++ni) {
                float y = fmaf(acc[h][oi][ni], s, sh);
                y = (y >= 0.f) ? y : 0.2f * y;
                out[(((size_t)b << 7) + o) * NPT + n0 + ni * 16 + tn] = y;
            }
        }
}

// ---------------------------------------------------------------------------
extern "C" void kernel_launch(void* const* d_in, const int* in_sizes, int n_in,
                              void* d_out, int out_size, void* d_ws, size_t ws_size,
                              hipStream_t stream)
{
    const float* xinfo   = (const float*)d_in[0];
    const float* feature = (const float*)d_in[1];
    const int*   nidx    = (const int*)  d_in[2];
    const float* Wq = (const float*)d_in[3];
    const float* Qg = (const float*)d_in[4];
    const float* Qb = (const float*)d_in[5];
    const float* Qm = (const float*)d_in[6];
    const float* Qv = (const float*)d_in[7];
    const float* Wk = (const float*)d_in[8];
    const float* Kg = (const float*)d_in[9];
    const float* Kb = (const float*)d_in[10];
    const float* Km = (const float*)d_in[11];
    const float* Kv = (const float*)d_in[12];
    const float* Wv = (const float*)d_in[13];
    const float* Vg = (const float*)d_in[14];
    const float* Vb = (const float*)d_in[15];
    const float* Vm = (const float*)d_in[16];
    const float* Vv = (const float*)d_in[17];
    const float* m2w = (const float*)d_in[18];
    const float* g2  = (const float*)d_in[19];
    const float* b2  = (const float*)d_in[20];
    const float* m2  = (const float*)d_in[21];
    const float* v2  = (const float*)d_in[22];
    float* out = (float*)d_out;

    // workspace: q/feat (in-place) 16 MiB, interleaved kv 32 MiB
    float* ws    = (float*)d_ws;
    float* qf    = ws;
    float* kvbuf = ws + (size_t)NB * NPT * 64;

    k_qkv<<<dim3(NPT / 64, NB), 256, 0, stream>>>(
        feature, Wq, Wk, Wv,
        Qg, Qb, Qm, Qv, Kg, Kb, Km, Kv, Vg, Vb, Vm, Vv,
        qf, kvbuf);

    k_attn<<<(NB * NPT) / 4, 256, 0, stream>>>(xinfo, nidx, qf, kvbuf);

    k_mlp2<<<dim3(NPT / 64, NB), 256, 0, stream>>>(qf, m2w, g2, b2, m2, v2, out);
}

// Round 3
// 140.461 us; speedup vs baseline: 1.2981x; 1.0849x over previous
//
#include <hip/hip_runtime.h>
#include <cstddef>

#define NPT 16384   // N
#define NB  4       // B
// C = 64, K = 16, O = 128

typedef float f32x4 __attribute__((ext_vector_type(4)));

// ---------------------------------------------------------------------------
// K1: fused 1x1 conv + BN(eps=1e-5) + ReLU for q, k, v.
// q out: [B][N][64]. k,v out INTERLEAVED: kv[p][c][2] = {k,v} so K2's gathers
// read one 512B-contiguous row per neighbor instead of two 256B rows.
// grid (N/64, B), block 256. Register-tiled GEMM, M=192 (q|k|v), tile n=64.
// ---------------------------------------------------------------------------
__global__ __launch_bounds__(256) void k_qkv(
    const float* __restrict__ feat_in,
    const float* __restrict__ Wq, const float* __restrict__ Wk, const float* __restrict__ Wv,
    const float* __restrict__ Qg, const float* __restrict__ Qb, const float* __restrict__ Qm, const float* __restrict__ Qv,
    const float* __restrict__ Kg, const float* __restrict__ Kb, const float* __restrict__ Km, const float* __restrict__ Kv,
    const float* __restrict__ Vg, const float* __restrict__ Vb, const float* __restrict__ Vm, const float* __restrict__ Vv,
    float* __restrict__ qo, float* __restrict__ kvo)
{
    __shared__ float wt[64][192];   // wt[c][t*64+o] = W_t[o][c]   (48 KiB)
    __shared__ float fs[64][64];    // fs[c][n_local]              (16 KiB)
    const int tid = threadIdx.x;
    const int b   = blockIdx.y;
    const int n0  = blockIdx.x * 64;

    // ---- stage weights transposed (unscaled; BN folded in epilogue) ----
    {
        const int o  = tid >> 2;          // 0..63
        const int cb = (tid & 3) * 16;    // 0,16,32,48
        const float* Ws[3] = {Wq, Wk, Wv};
        #pragma unroll
        for (int t = 0; t < 3; ++t) {
            const float4* src = reinterpret_cast<const float4*>(Ws[t] + o * 64 + cb);
            #pragma unroll
            for (int k4 = 0; k4 < 4; ++k4) {
                float4 w4 = src[k4];
                wt[cb + k4 * 4 + 0][t * 64 + o] = w4.x;
                wt[cb + k4 * 4 + 1][t * 64 + o] = w4.y;
                wt[cb + k4 * 4 + 2][t * 64 + o] = w4.z;
                wt[cb + k4 * 4 + 3][t * 64 + o] = w4.w;
            }
        }
    }
    // ---- stage feature tile: fs[c][n] from feature[b][c][n0+n] ----
    #pragma unroll
    for (int i = 0; i < 16; ++i) {
        int flat = tid + i * 256;       // 4096 elements
        int c = flat >> 6, n = flat & 63;
        fs[c][n] = feat_in[((size_t)b * 64 + c) * NPT + n0 + n];
    }
    __syncthreads();

    const int to = tid & 15;   // o-quad
    const int tn = tid >> 4;   // n-quad
    float acc[3][4][4];
    #pragma unroll
    for (int t = 0; t < 3; ++t)
        #pragma unroll
        for (int i = 0; i < 4; ++i)
            #pragma unroll
            for (int j = 0; j < 4; ++j) acc[t][i][j] = 0.f;

    #pragma unroll 4
    for (int c = 0; c < 64; ++c) {
        float4 f4  = *reinterpret_cast<const float4*>(&fs[c][tn * 4]);
        float4 wq4 = *reinterpret_cast<const float4*>(&wt[c][to * 4]);
        float4 wk4 = *reinterpret_cast<const float4*>(&wt[c][64 + to * 4]);
        float4 wv4 = *reinterpret_cast<const float4*>(&wt[c][128 + to * 4]);
        float fr[4]    = {f4.x, f4.y, f4.z, f4.w};
        float wr[3][4] = {{wq4.x, wq4.y, wq4.z, wq4.w},
                          {wk4.x, wk4.y, wk4.z, wk4.w},
                          {wv4.x, wv4.y, wv4.z, wv4.w}};
        #pragma unroll
        for (int t = 0; t < 3; ++t)
            #pragma unroll
            for (int oi = 0; oi < 4; ++oi)
                #pragma unroll
                for (int nn = 0; nn < 4; ++nn)
                    acc[t][oi][nn] = fmaf(wr[t][oi], fr[nn], acc[t][oi][nn]);
    }

    // ---- epilogue: BN fold + ReLU ----
    float scq[4], shq[4], sck[4], shk[4], scv[4], shv[4];
    #pragma unroll
    for (int oi = 0; oi < 4; ++oi) {
        int o = to * 4 + oi;
        float s;
        s = Qg[o] * rsqrtf(Qv[o] + 1e-5f); scq[oi] = s; shq[oi] = Qb[o] - Qm[o] * s;
        s = Kg[o] * rsqrtf(Kv[o] + 1e-5f); sck[oi] = s; shk[oi] = Kb[o] - Km[o] * s;
        s = Vg[o] * rsqrtf(Vv[o] + 1e-5f); scv[oi] = s; shv[oi] = Vb[o] - Vm[o] * s;
    }
    #pragma unroll
    for (int nn = 0; nn < 4; ++nn) {
        const size_t pidx = (size_t)b * NPT + n0 + tn * 4 + nn;
        // q: [p][c]
        float4 rq;
        rq.x = fmaxf(fmaf(acc[0][0][nn], scq[0], shq[0]), 0.f);
        rq.y = fmaxf(fmaf(acc[0][1][nn], scq[1], shq[1]), 0.f);
        rq.z = fmaxf(fmaf(acc[0][2][nn], scq[2], shq[2]), 0.f);
        rq.w = fmaxf(fmaf(acc[0][3][nn], scq[3], shq[3]), 0.f);
        *reinterpret_cast<float4*>(qo + (pidx << 6) + to * 4) = rq;
        // kv interleaved: [p][c][{k,v}] -- keep DEFAULT caching: this is the
        // only buffer with reuse; we want it resident in L3 for K2's gathers.
        float rk[4], rv[4];
        #pragma unroll
        for (int oi = 0; oi < 4; ++oi) {
            rk[oi] = fmaxf(fmaf(acc[1][oi][nn], sck[oi], shk[oi]), 0.f);
            rv[oi] = fmaxf(fmaf(acc[2][oi][nn], scv[oi], shv[oi]), 0.f);
        }
        float* dst = kvo + (pidx << 7) + to * 8;
        *reinterpret_cast<float4*>(dst)     = make_float4(rk[0], rv[0], rk[1], rv[1]);
        *reinterpret_cast<float4*>(dst + 4) = make_float4(rk[2], rv[2], rk[3], rv[3]);
    }
}

// ---------------------------------------------------------------------------
// K2: gather + attention + weighted sum. One wave per point, lane = channel.
// x_info (268 MB, zero reuse) is loaded NON-TEMPORAL so the stream does not
// thrash L3: the kv buffer (32 MiB, ~16x reuse via gathers) stays L3-resident
// and gathers become L3 hits instead of HBM misses.
// Writes feat back over q IN PLACE (each address touched by exactly one lane).
// grid = B*N/4 blocks of 256 threads (4 waves = 4 points per block).
// ---------------------------------------------------------------------------
__global__ __launch_bounds__(256) void k_attn(
    const float* __restrict__ xinfo,
    const int*   __restrict__ nidx,
    float*                    qfeat,      // q in, feat out (aliased on purpose)
    const float* __restrict__ kv)
{
    __shared__ float xs[64][68];   // [c][pl*16+j], pad 4 -> <=2-way bank alias
    const int tid  = threadIdx.x;
    const int lane = tid & 63;
    const int wv   = tid >> 6;
    const int p0   = blockIdx.x * 4;
    const int b    = p0 >> 14;
    const int n0   = p0 & 16383;
    const int p    = p0 + wv;

    // idx first: the gathers depend on it
    int idxv = nidx[((size_t)p << 4) + (lane & 15)];
    float qc = __builtin_nontemporal_load(qfeat + ((size_t)p << 6) + lane);

    // ---- cooperative x_info tile load (nt): 4096 floats = 4 x f32x4/thread ----
    const float* xbase = xinfo + (((size_t)b * 64) * NPT + n0) * 16;
    f32x4 xr[4];
    #pragma unroll
    for (int i = 0; i < 4; ++i) {
        int f = tid + i * 256;        // float4 index in tile, 0..1023
        int c = f >> 4, s = f & 15;   // channel, 16B-segment within 256B run
        xr[i] = __builtin_nontemporal_load(
            reinterpret_cast<const f32x4*>(xbase + (size_t)c * (NPT * 16) + s * 4));
    }
    #pragma unroll
    for (int i = 0; i < 4; ++i) {
        int f = tid + i * 256;
        int c = f >> 4, s = f & 15;
        *reinterpret_cast<f32x4*>(&xs[c][s * 4]) = xr[i];
    }

    // ---- gathers: per j, 64 lanes read one contiguous 512B kv row (cached) ----
    float kgv[16], vgv[16];
    const float2* kv2 = reinterpret_cast<const float2*>(kv);
    #pragma unroll
    for (int j = 0; j < 16; ++j) {
        int nj = __shfl(idxv, j);
        float2 g = kv2[(((size_t)((b << 14) | nj)) << 6) + lane];
        kgv[j] = g.x; vgv[j] = g.y;
    }

    __syncthreads();

    // ---- softmax over K=16, fully in-lane ----
    float w[16];
    #pragma unroll
    for (int k4 = 0; k4 < 4; ++k4) {
        float4 x4 = *reinterpret_cast<const float4*>(&xs[lane][wv * 16 + k4 * 4]);
        w[k4 * 4 + 0] = x4.x * (kgv[k4 * 4 + 0] - qc);
        w[k4 * 4 + 1] = x4.y * (kgv[k4 * 4 + 1] - qc);
        w[k4 * 4 + 2] = x4.z * (kgv[k4 * 4 + 2] - qc);
        w[k4 * 4 + 3] = x4.w * (kgv[k4 * 4 + 3] - qc);
    }

    float mx = w[0];
    #pragma unroll
    for (int j = 1; j < 16; ++j) mx = fmaxf(mx, w[j]);

    float es = 0.f, fsum = 0.f;
    #pragma unroll
    for (int j = 0; j < 16; ++j) {
        float e = __expf(w[j] - mx);
        es += e;
        fsum = fmaf(e, vgv[j], fsum);
    }

    qfeat[((size_t)p << 6) + lane] = fsum / es;   // feat, in place over q
}

// ---------------------------------------------------------------------------
// K3: mlp2 = 1x1 conv (O=128) + BN(eps=1e-6) + LeakyReLU(0.2).
// grid (N/64, B), block 256. Tile 128o x 64n; wt & feat transposed into LDS.
// Output [B][128][N]; float4 NT stores (256B per 16-lane segment).
// ---------------------------------------------------------------------------
__global__ __launch_bounds__(256) void k_mlp2(
    const float* __restrict__ feat,
    const float* __restrict__ m2w,
    const float* __restrict__ g2, const float* __restrict__ b2,
    const float* __restrict__ m2, const float* __restrict__ v2,
    float* __restrict__ out)
{
    __shared__ float wt [64][132];  // wt[c][o], padded (33 KiB)
    __shared__ float fsh[64][68];   // fsh[c][n], padded (17 KiB)
    const int tid = threadIdx.x;
    const int b   = blockIdx.y;
    const int n0  = blockIdx.x * 64;

    // ---- stage wt[c][o] from m2w[o][c] ----
    {
        const int o  = tid >> 1;          // 0..127
        const int ch = (tid & 1) * 32;    // 0 or 32
        const float4* src = reinterpret_cast<const float4*>(m2w + o * 64 + ch);
        #pragma unroll
        for (int k4 = 0; k4 < 8; ++k4) {
            float4 w4 = src[k4];
            wt[ch + k4 * 4 + 0][o] = w4.x;
            wt[ch + k4 * 4 + 1][o] = w4.y;
            wt[ch + k4 * 4 + 2][o] = w4.z;
            wt[ch + k4 * 4 + 3][o] = w4.w;
        }
    }
    // ---- stage fsh[c][n] from feat[b][n0+n][c] ----
    {
        const int c4 = tid & 15;       // float4 index along c
        const int nl = tid >> 4;       // 0..15
        #pragma unroll
        for (int i = 0; i < 4; ++i) {
            int n = nl + i * 16;
            float4 f4 = *reinterpret_cast<const float4*>(
                feat + (((size_t)b * NPT + n0 + n) << 6) + c4 * 4);
            fsh[c4 * 4 + 0][n] = f4.x;
            fsh[c4 * 4 + 1][n] = f4.y;
            fsh[c4 * 4 + 2][n] = f4.z;
            fsh[c4 * 4 + 3][n] = f4.w;
        }
    }
    __syncthreads();

    const int tn = tid & 15;   // lane's n-quad: n = tn*4 .. tn*4+3 (float4 stores)
    const int to = tid >> 4;   // 0..15 -> o quads {to*4..+3} and {64+to*4..+3}
    float acc[2][4][4];        // [half][oi][ni]
    #pragma unroll
    for (int h = 0; h < 2; ++h)
        #pragma unroll
        for (int i = 0; i < 4; ++i)
            #pragma unroll
            for (int j = 0; j < 4; ++j) acc[h][i][j] = 0.f;

    #pragma unroll 4
    for (int c = 0; c < 64; ++c) {
        float4 wa = *reinterpret_cast<const float4*>(&wt[c][to * 4]);
        float4 wb = *reinterpret_cast<const float4*>(&wt[c][64 + to * 4]);
        float4 f4 = *reinterpret_cast<const float4*>(&fsh[c][tn * 4]);
        float wra[4] = {wa.x, wa.y, wa.z, wa.w};
        float wrb[4] = {wb.x, wb.y, wb.z, wb.w};
        float fr[4]  = {f4.x, f4.y, f4.z, f4.w};
        #pragma unroll
        for (int oi = 0; oi < 4; ++oi)
            #pragma unroll
            for (int ni = 0; ni < 4; ++ni) {
                acc[0][oi][ni] = fmaf(wra[oi], fr[ni], acc[0][oi][ni]);
                acc[1][oi][ni] = fmaf(wrb[oi], fr[ni], acc[1][oi][ni]);
            }
    }

    #pragma unroll
    for (int h = 0; h < 2; ++h)
        #pragma unroll
        for (int oi = 0; oi < 4; ++oi) {
            int o = h * 64 + to * 4 + oi;
            float s  = g2[o] * rsqrtf(v2[o] + 1e-6f);
            float sh = b2[o] - m2[o] * s;
            f32x4 r;
            #pragma unroll
            for (int ni = 0; ni < 4; ++ni) {
                float y = fmaf(acc[h][oi][ni], s, sh);
                r[ni] = (y >= 0.f) ? y : 0.2f * y;
            }
            __builtin_nontemporal_store(r, reinterpret_cast<f32x4*>(
                out + (((size_t)b << 7) + o) * NPT + n0 + tn * 4));
        }
}

// ---------------------------------------------------------------------------
extern "C" void kernel_launch(void* const* d_in, const int* in_sizes, int n_in,
                              void* d_out, int out_size, void* d_ws, size_t ws_size,
                              hipStream_t stream)
{
    const float* xinfo   = (const float*)d_in[0];
    const float* feature = (const float*)d_in[1];
    const int*   nidx    = (const int*)  d_in[2];
    const float* Wq = (const float*)d_in[3];
    const float* Qg = (const float*)d_in[4];
    const float* Qb = (const float*)d_in[5];
    const float* Qm = (const float*)d_in[6];
    const float* Qv = (const float*)d_in[7];
    const float* Wk = (const float*)d_in[8];
    const float* Kg = (const float*)d_in[9];
    const float* Kb = (const float*)d_in[10];
    const float* Km = (const float*)d_in[11];
    const float* Kv = (const float*)d_in[12];
    const float* Wv = (const float*)d_in[13];
    const float* Vg = (const float*)d_in[14];
    const float* Vb = (const float*)d_in[15];
    const float* Vm = (const float*)d_in[16];
    const float* Vv = (const float*)d_in[17];
    const float* m2w = (const float*)d_in[18];
    const float* g2  = (const float*)d_in[19];
    const float* b2  = (const float*)d_in[20];
    const float* m2  = (const float*)d_in[21];
    const float* v2  = (const float*)d_in[22];
    float* out = (float*)d_out;

    // workspace: q/feat (in-place) 16 MiB, interleaved kv 32 MiB
    float* ws    = (float*)d_ws;
    float* qf    = ws;
    float* kvbuf = ws + (size_t)NB * NPT * 64;

    k_qkv<<<dim3(NPT / 64, NB), 256, 0, stream>>>(
        feature, Wq, Wk, Wv,
        Qg, Qb, Qm, Qv, Kg, Kb, Km, Kv, Vg, Vb, Vm, Vv,
        qf, kvbuf);

    k_attn<<<(NB * NPT) / 4, 256, 0, stream>>>(xinfo, nidx, qf, kvbuf);

    k_mlp2<<<dim3(NPT / 64, NB), 256, 0, stream>>>(qf, m2w, g2, b2, m2, v2, out);
}

// Round 4
// 113.835 us; speedup vs baseline: 1.6017x; 1.2339x over previous
//
#include <hip/hip_runtime.h>
#include <cstddef>
#include <cstdint>

#define NPT 16384   // N
#define NB  4       // B
// C = 64, K = 16, O = 128

typedef float    f32x4 __attribute__((ext_vector_type(4)));
typedef uint32_t u32x4 __attribute__((ext_vector_type(4)));

__device__ __forceinline__ uint32_t bf16_rtne(float f) {
    uint32_t u = __builtin_bit_cast(uint32_t, f);
    return (u + 0x7FFFu + ((u >> 16) & 1u)) >> 16;
}

// ---------------------------------------------------------------------------
// K1: fused 1x1 conv + BN(eps=1e-5) + ReLU for q, k, v.
// q out: [B][N][64] fp32. k,v out PACKED bf16: kv[p][c] = (bf16(k)<<16)|bf16(v)
// -> one 256B row per point; per-batch working set 4 MiB = one XCD L2.
// grid (N/64, B), block 256. Register-tiled GEMM, M=192 (q|k|v), tile n=64.
// ---------------------------------------------------------------------------
__global__ __launch_bounds__(256) void k_qkv(
    const float* __restrict__ feat_in,
    const float* __restrict__ Wq, const float* __restrict__ Wk, const float* __restrict__ Wv,
    const float* __restrict__ Qg, const float* __restrict__ Qb, const float* __restrict__ Qm, const float* __restrict__ Qv,
    const float* __restrict__ Kg, const float* __restrict__ Kb, const float* __restrict__ Km, const float* __restrict__ Kv,
    const float* __restrict__ Vg, const float* __restrict__ Vb, const float* __restrict__ Vm, const float* __restrict__ Vv,
    float* __restrict__ qo, uint32_t* __restrict__ kvo)
{
    __shared__ float wt[64][192];   // wt[c][t*64+o] = W_t[o][c]   (48 KiB)
    __shared__ float fs[64][64];    // fs[c][n_local]              (16 KiB)
    const int tid = threadIdx.x;
    const int b   = blockIdx.y;
    const int n0  = blockIdx.x * 64;

    // ---- stage weights transposed (unscaled; BN folded in epilogue) ----
    {
        const int o  = tid >> 2;          // 0..63
        const int cb = (tid & 3) * 16;    // 0,16,32,48
        const float* Ws[3] = {Wq, Wk, Wv};
        #pragma unroll
        for (int t = 0; t < 3; ++t) {
            const float4* src = reinterpret_cast<const float4*>(Ws[t] + o * 64 + cb);
            #pragma unroll
            for (int k4 = 0; k4 < 4; ++k4) {
                float4 w4 = src[k4];
                wt[cb + k4 * 4 + 0][t * 64 + o] = w4.x;
                wt[cb + k4 * 4 + 1][t * 64 + o] = w4.y;
                wt[cb + k4 * 4 + 2][t * 64 + o] = w4.z;
                wt[cb + k4 * 4 + 3][t * 64 + o] = w4.w;
            }
        }
    }
    // ---- stage feature tile: fs[c][n] from feature[b][c][n0+n] ----
    #pragma unroll
    for (int i = 0; i < 16; ++i) {
        int flat = tid + i * 256;       // 4096 elements
        int c = flat >> 6, n = flat & 63;
        fs[c][n] = feat_in[((size_t)b * 64 + c) * NPT + n0 + n];
    }
    __syncthreads();

    const int to = tid & 15;   // o-quad
    const int tn = tid >> 4;   // n-quad
    float acc[3][4][4];
    #pragma unroll
    for (int t = 0; t < 3; ++t)
        #pragma unroll
        for (int i = 0; i < 4; ++i)
            #pragma unroll
            for (int j = 0; j < 4; ++j) acc[t][i][j] = 0.f;

    #pragma unroll 4
    for (int c = 0; c < 64; ++c) {
        float4 f4  = *reinterpret_cast<const float4*>(&fs[c][tn * 4]);
        float4 wq4 = *reinterpret_cast<const float4*>(&wt[c][to * 4]);
        float4 wk4 = *reinterpret_cast<const float4*>(&wt[c][64 + to * 4]);
        float4 wv4 = *reinterpret_cast<const float4*>(&wt[c][128 + to * 4]);
        float fr[4]    = {f4.x, f4.y, f4.z, f4.w};
        float wr[3][4] = {{wq4.x, wq4.y, wq4.z, wq4.w},
                          {wk4.x, wk4.y, wk4.z, wk4.w},
                          {wv4.x, wv4.y, wv4.z, wv4.w}};
        #pragma unroll
        for (int t = 0; t < 3; ++t)
            #pragma unroll
            for (int oi = 0; oi < 4; ++oi)
                #pragma unroll
                for (int nn = 0; nn < 4; ++nn)
                    acc[t][oi][nn] = fmaf(wr[t][oi], fr[nn], acc[t][oi][nn]);
    }

    // ---- epilogue: BN fold + ReLU; pack k,v -> bf16x2 ----
    float scq[4], shq[4], sck[4], shk[4], scv[4], shv[4];
    #pragma unroll
    for (int oi = 0; oi < 4; ++oi) {
        int o = to * 4 + oi;
        float s;
        s = Qg[o] * rsqrtf(Qv[o] + 1e-5f); scq[oi] = s; shq[oi] = Qb[o] - Qm[o] * s;
        s = Kg[o] * rsqrtf(Kv[o] + 1e-5f); sck[oi] = s; shk[oi] = Kb[o] - Km[o] * s;
        s = Vg[o] * rsqrtf(Vv[o] + 1e-5f); scv[oi] = s; shv[oi] = Vb[o] - Vm[o] * s;
    }
    #pragma unroll
    for (int nn = 0; nn < 4; ++nn) {
        const size_t pidx = (size_t)b * NPT + n0 + tn * 4 + nn;
        // q: [p][c] fp32
        float4 rq;
        rq.x = fmaxf(fmaf(acc[0][0][nn], scq[0], shq[0]), 0.f);
        rq.y = fmaxf(fmaf(acc[0][1][nn], scq[1], shq[1]), 0.f);
        rq.z = fmaxf(fmaf(acc[0][2][nn], scq[2], shq[2]), 0.f);
        rq.w = fmaxf(fmaf(acc[0][3][nn], scq[3], shq[3]), 0.f);
        *reinterpret_cast<float4*>(qo + (pidx << 6) + to * 4) = rq;
        // kv packed: hi16 = k, lo16 = v (keep DEFAULT caching: reused by K2)
        u32x4 pk;
        #pragma unroll
        for (int oi = 0; oi < 4; ++oi) {
            float rk = fmaxf(fmaf(acc[1][oi][nn], sck[oi], shk[oi]), 0.f);
            float rv = fmaxf(fmaf(acc[2][oi][nn], scv[oi], shv[oi]), 0.f);
            pk[oi] = (bf16_rtne(rk) << 16) | bf16_rtne(rv);
        }
        *reinterpret_cast<u32x4*>(kvo + (pidx << 6) + to * 4) = pk;
    }
}

// ---------------------------------------------------------------------------
// K2: gather + attention + weighted sum. One wave per point, lane = channel.
// x_info (268 MB, zero reuse) loaded NON-TEMPORAL (doesn't thrash caches).
// kv gathers: one 256B bf16x2 row per neighbor; 4 MiB/batch working set
// stays L2-resident (all XCDs process the same batch concurrently).
// Writes feat back over q IN PLACE (each address touched by exactly one lane).
// grid = B*N/4 blocks of 256 threads (4 waves = 4 points per block).
// ---------------------------------------------------------------------------
__global__ __launch_bounds__(256) void k_attn(
    const float*    __restrict__ xinfo,
    const int*      __restrict__ nidx,
    float*                       qfeat,   // q in, feat out (aliased on purpose)
    const uint32_t* __restrict__ kv)
{
    __shared__ float xs[64][68];   // [c][pl*16+j], pad 4 -> <=2-way bank alias
    const int tid  = threadIdx.x;
    const int lane = tid & 63;
    const int wv   = tid >> 6;
    const int p0   = blockIdx.x * 4;
    const int b    = p0 >> 14;
    const int n0   = p0 & 16383;
    const int p    = p0 + wv;

    // idx first: the gathers depend on it
    int idxv = nidx[((size_t)p << 4) + (lane & 15)];
    float qc = __builtin_nontemporal_load(qfeat + ((size_t)p << 6) + lane);

    // ---- cooperative x_info tile load (nt): 4096 floats = 4 x f32x4/thread ----
    const float* xbase = xinfo + (((size_t)b * 64) * NPT + n0) * 16;
    f32x4 xr[4];
    #pragma unroll
    for (int i = 0; i < 4; ++i) {
        int f = tid + i * 256;        // float4 index in tile, 0..1023
        int c = f >> 4, s = f & 15;   // channel, 16B-segment within 256B run
        xr[i] = __builtin_nontemporal_load(
            reinterpret_cast<const f32x4*>(xbase + (size_t)c * (NPT * 16) + s * 4));
    }

    // ---- gathers: per j, 64 lanes read one contiguous 256B kv row (cached) ----
    float kgv[16], vgv[16];
    #pragma unroll
    for (int j = 0; j < 16; ++j) {
        int nj = __shfl(idxv, j);
        uint32_t g = kv[(((size_t)((b << 14) | nj)) << 6) + lane];
        kgv[j] = __builtin_bit_cast(float, g & 0xFFFF0000u);
        vgv[j] = __builtin_bit_cast(float, g << 16);
    }

    #pragma unroll
    for (int i = 0; i < 4; ++i) {
        int f = tid + i * 256;
        int c = f >> 4, s = f & 15;
        *reinterpret_cast<f32x4*>(&xs[c][s * 4]) = xr[i];
    }
    __syncthreads();

    // ---- softmax over K=16, fully in-lane ----
    float w[16];
    #pragma unroll
    for (int k4 = 0; k4 < 4; ++k4) {
        float4 x4 = *reinterpret_cast<const float4*>(&xs[lane][wv * 16 + k4 * 4]);
        w[k4 * 4 + 0] = x4.x * (kgv[k4 * 4 + 0] - qc);
        w[k4 * 4 + 1] = x4.y * (kgv[k4 * 4 + 1] - qc);
        w[k4 * 4 + 2] = x4.z * (kgv[k4 * 4 + 2] - qc);
        w[k4 * 4 + 3] = x4.w * (kgv[k4 * 4 + 3] - qc);
    }

    float mx = w[0];
    #pragma unroll
    for (int j = 1; j < 16; ++j) mx = fmaxf(mx, w[j]);

    float es = 0.f, fsum = 0.f;
    #pragma unroll
    for (int j = 0; j < 16; ++j) {
        float e = __expf(w[j] - mx);
        es += e;
        fsum = fmaf(e, vgv[j], fsum);
    }

    qfeat[((size_t)p << 6) + lane] = fsum / es;   // feat, in place over q
}

// ---------------------------------------------------------------------------
// K3: mlp2 = 1x1 conv (O=128) + BN(eps=1e-6) + LeakyReLU(0.2).
// grid (N/64, B), block 256. Tile 128o x 64n; wt & feat transposed into LDS.
// Output [B][128][N]; float4 NT stores (256B per 16-lane segment).
// ---------------------------------------------------------------------------
__global__ __launch_bounds__(256) void k_mlp2(
    const float* __restrict__ feat,
    const float* __restrict__ m2w,
    const float* __restrict__ g2, const float* __restrict__ b2,
    const float* __restrict__ m2, const float* __restrict__ v2,
    float* __restrict__ out)
{
    __shared__ float wt [64][132];  // wt[c][o], padded (33 KiB)
    __shared__ float fsh[64][68];   // fsh[c][n], padded (17 KiB)
    const int tid = threadIdx.x;
    const int b   = blockIdx.y;
    const int n0  = blockIdx.x * 64;

    // ---- stage wt[c][o] from m2w[o][c] ----
    {
        const int o  = tid >> 1;          // 0..127
        const int ch = (tid & 1) * 32;    // 0 or 32
        const float4* src = reinterpret_cast<const float4*>(m2w + o * 64 + ch);
        #pragma unroll
        for (int k4 = 0; k4 < 8; ++k4) {
            float4 w4 = src[k4];
            wt[ch + k4 * 4 + 0][o] = w4.x;
            wt[ch + k4 * 4 + 1][o] = w4.y;
            wt[ch + k4 * 4 + 2][o] = w4.z;
            wt[ch + k4 * 4 + 3][o] = w4.w;
        }
    }
    // ---- stage fsh[c][n] from feat[b][n0+n][c] ----
    {
        const int c4 = tid & 15;       // float4 index along c
        const int nl = tid >> 4;       // 0..15
        #pragma unroll
        for (int i = 0; i < 4; ++i) {
            int n = nl + i * 16;
            float4 f4 = *reinterpret_cast<const float4*>(
                feat + (((size_t)b * NPT + n0 + n) << 6) + c4 * 4);
            fsh[c4 * 4 + 0][n] = f4.x;
            fsh[c4 * 4 + 1][n] = f4.y;
            fsh[c4 * 4 + 2][n] = f4.z;
            fsh[c4 * 4 + 3][n] = f4.w;
        }
    }
    __syncthreads();

    const int tn = tid & 15;   // lane's n-quad: n = tn*4 .. tn*4+3 (float4 stores)
    const int to = tid >> 4;   // 0..15 -> o quads {to*4..+3} and {64+to*4..+3}
    float acc[2][4][4];        // [half][oi][ni]
    #pragma unroll
    for (int h = 0; h < 2; ++h)
        #pragma unroll
        for (int i = 0; i < 4; ++i)
            #pragma unroll
            for (int j = 0; j < 4; ++j) acc[h][i][j] = 0.f;

    #pragma unroll 4
    for (int c = 0; c < 64; ++c) {
        float4 wa = *reinterpret_cast<const float4*>(&wt[c][to * 4]);
        float4 wb = *reinterpret_cast<const float4*>(&wt[c][64 + to * 4]);
        float4 f4 = *reinterpret_cast<const float4*>(&fsh[c][tn * 4]);
        float wra[4] = {wa.x, wa.y, wa.z, wa.w};
        float wrb[4] = {wb.x, wb.y, wb.z, wb.w};
        float fr[4]  = {f4.x, f4.y, f4.z, f4.w};
        #pragma unroll
        for (int oi = 0; oi < 4; ++oi)
            #pragma unroll
            for (int ni = 0; ni < 4; ++ni) {
                acc[0][oi][ni] = fmaf(wra[oi], fr[ni], acc[0][oi][ni]);
                acc[1][oi][ni] = fmaf(wrb[oi], fr[ni], acc[1][oi][ni]);
            }
    }

    #pragma unroll
    for (int h = 0; h < 2; ++h)
        #pragma unroll
        for (int oi = 0; oi < 4; ++oi) {
            int o = h * 64 + to * 4 + oi;
            float s  = g2[o] * rsqrtf(v2[o] + 1e-6f);
            float sh = b2[o] - m2[o] * s;
            f32x4 r;
            #pragma unroll
            for (int ni = 0; ni < 4; ++ni) {
                float y = fmaf(acc[h][oi][ni], s, sh);
                r[ni] = (y >= 0.f) ? y : 0.2f * y;
            }
            __builtin_nontemporal_store(r, reinterpret_cast<f32x4*>(
                out + (((size_t)b << 7) + o) * NPT + n0 + tn * 4));
        }
}

// ---------------------------------------------------------------------------
extern "C" void kernel_launch(void* const* d_in, const int* in_sizes, int n_in,
                              void* d_out, int out_size, void* d_ws, size_t ws_size,
                              hipStream_t stream)
{
    const float* xinfo   = (const float*)d_in[0];
    const float* feature = (const float*)d_in[1];
    const int*   nidx    = (const int*)  d_in[2];
    const float* Wq = (const float*)d_in[3];
    const float* Qg = (const float*)d_in[4];
    const float* Qb = (const float*)d_in[5];
    const float* Qm = (const float*)d_in[6];
    const float* Qv = (const float*)d_in[7];
    const float* Wk = (const float*)d_in[8];
    const float* Kg = (const float*)d_in[9];
    const float* Kb = (const float*)d_in[10];
    const float* Km = (const float*)d_in[11];
    const float* Kv = (const float*)d_in[12];
    const float* Wv = (const float*)d_in[13];
    const float* Vg = (const float*)d_in[14];
    const float* Vb = (const float*)d_in[15];
    const float* Vm = (const float*)d_in[16];
    const float* Vv = (const float*)d_in[17];
    const float* m2w = (const float*)d_in[18];
    const float* g2  = (const float*)d_in[19];
    const float* b2  = (const float*)d_in[20];
    const float* m2  = (const float*)d_in[21];
    const float* v2  = (const float*)d_in[22];
    float* out = (float*)d_out;

    // workspace: q/feat (in-place) 16 MiB fp32, packed kv 16 MiB u32
    float*    ws    = (float*)d_ws;
    float*    qf    = ws;
    uint32_t* kvbuf = (uint32_t*)(ws + (size_t)NB * NPT * 64);

    k_qkv<<<dim3(NPT / 64, NB), 256, 0, stream>>>(
        feature, Wq, Wk, Wv,
        Qg, Qb, Qm, Qv, Kg, Kb, Km, Kv, Vg, Vb, Vm, Vv,
        qf, kvbuf);

    k_attn<<<(NB * NPT) / 4, 256, 0, stream>>>(xinfo, nidx, qf, kvbuf);

    k_mlp2<<<dim3(NPT / 64, NB), 256, 0, stream>>>(qf, m2w, g2, b2, m2, v2, out);
}

// Round 5
// 113.797 us; speedup vs baseline: 1.6023x; 1.0003x over previous
//
#include <hip/hip_runtime.h>
#include <cstddef>
#include <cstdint>

#define NPT 16384   // N
#define NB  4       // B
// C = 64, K = 16, O = 128

typedef float    f32x4 __attribute__((ext_vector_type(4)));
typedef uint32_t u32x4 __attribute__((ext_vector_type(4)));

__device__ __forceinline__ uint32_t bf16_rtne(float f) {
    uint32_t u = __builtin_bit_cast(uint32_t, f);
    return (u + 0x7FFFu + ((u >> 16) & 1u)) >> 16;
}

// ---------------------------------------------------------------------------
// K1: fused 1x1 conv + BN(eps=1e-5) + ReLU for q, k, v.
// q out: [B][N][64] fp32. k,v out PACKED bf16: kv[p][c] = (bf16(k)<<16)|bf16(v)
// -> one 256B row per point; per-batch working set 4 MiB ~ one XCD L2.
// grid (N/64, B), block 256. Register-tiled GEMM, M=192 (q|k|v), tile n=64.
// ---------------------------------------------------------------------------
__global__ __launch_bounds__(256) void k_qkv(
    const float* __restrict__ feat_in,
    const float* __restrict__ Wq, const float* __restrict__ Wk, const float* __restrict__ Wv,
    const float* __restrict__ Qg, const float* __restrict__ Qb, const float* __restrict__ Qm, const float* __restrict__ Qv,
    const float* __restrict__ Kg, const float* __restrict__ Kb, const float* __restrict__ Km, const float* __restrict__ Kv,
    const float* __restrict__ Vg, const float* __restrict__ Vb, const float* __restrict__ Vm, const float* __restrict__ Vv,
    float* __restrict__ qo, uint32_t* __restrict__ kvo)
{
    __shared__ float wt[64][192];   // wt[c][t*64+o] = W_t[o][c]   (48 KiB)
    __shared__ float fs[64][64];    // fs[c][n_local]              (16 KiB)
    const int tid = threadIdx.x;
    const int b   = blockIdx.y;
    const int n0  = blockIdx.x * 64;

    // ---- stage weights transposed (unscaled; BN folded in epilogue) ----
    {
        const int o  = tid >> 2;          // 0..63
        const int cb = (tid & 3) * 16;    // 0,16,32,48
        const float* Ws[3] = {Wq, Wk, Wv};
        #pragma unroll
        for (int t = 0; t < 3; ++t) {
            const float4* src = reinterpret_cast<const float4*>(Ws[t] + o * 64 + cb);
            #pragma unroll
            for (int k4 = 0; k4 < 4; ++k4) {
                float4 w4 = src[k4];
                wt[cb + k4 * 4 + 0][t * 64 + o] = w4.x;
                wt[cb + k4 * 4 + 1][t * 64 + o] = w4.y;
                wt[cb + k4 * 4 + 2][t * 64 + o] = w4.z;
                wt[cb + k4 * 4 + 3][t * 64 + o] = w4.w;
            }
        }
    }
    // ---- stage feature tile: fs[c][n] from feature[b][c][n0+n] ----
    #pragma unroll
    for (int i = 0; i < 16; ++i) {
        int flat = tid + i * 256;       // 4096 elements
        int c = flat >> 6, n = flat & 63;
        fs[c][n] = feat_in[((size_t)b * 64 + c) * NPT + n0 + n];
    }
    __syncthreads();

    const int to = tid & 15;   // o-quad
    const int tn = tid >> 4;   // n-quad
    float acc[3][4][4];
    #pragma unroll
    for (int t = 0; t < 3; ++t)
        #pragma unroll
        for (int i = 0; i < 4; ++i)
            #pragma unroll
            for (int j = 0; j < 4; ++j) acc[t][i][j] = 0.f;

    #pragma unroll 4
    for (int c = 0; c < 64; ++c) {
        float4 f4  = *reinterpret_cast<const float4*>(&fs[c][tn * 4]);
        float4 wq4 = *reinterpret_cast<const float4*>(&wt[c][to * 4]);
        float4 wk4 = *reinterpret_cast<const float4*>(&wt[c][64 + to * 4]);
        float4 wv4 = *reinterpret_cast<const float4*>(&wt[c][128 + to * 4]);
        float fr[4]    = {f4.x, f4.y, f4.z, f4.w};
        float wr[3][4] = {{wq4.x, wq4.y, wq4.z, wq4.w},
                          {wk4.x, wk4.y, wk4.z, wk4.w},
                          {wv4.x, wv4.y, wv4.z, wv4.w}};
        #pragma unroll
        for (int t = 0; t < 3; ++t)
            #pragma unroll
            for (int oi = 0; oi < 4; ++oi)
                #pragma unroll
                for (int nn = 0; nn < 4; ++nn)
                    acc[t][oi][nn] = fmaf(wr[t][oi], fr[nn], acc[t][oi][nn]);
    }

    // ---- epilogue: BN fold + ReLU; pack k,v -> bf16x2 ----
    float scq[4], shq[4], sck[4], shk[4], scv[4], shv[4];
    #pragma unroll
    for (int oi = 0; oi < 4; ++oi) {
        int o = to * 4 + oi;
        float s;
        s = Qg[o] * rsqrtf(Qv[o] + 1e-5f); scq[oi] = s; shq[oi] = Qb[o] - Qm[o] * s;
        s = Kg[o] * rsqrtf(Kv[o] + 1e-5f); sck[oi] = s; shk[oi] = Kb[o] - Km[o] * s;
        s = Vg[o] * rsqrtf(Vv[o] + 1e-5f); scv[oi] = s; shv[oi] = Vb[o] - Vm[o] * s;
    }
    #pragma unroll
    for (int nn = 0; nn < 4; ++nn) {
        const size_t pidx = (size_t)b * NPT + n0 + tn * 4 + nn;
        // q: [p][c] fp32
        float4 rq;
        rq.x = fmaxf(fmaf(acc[0][0][nn], scq[0], shq[0]), 0.f);
        rq.y = fmaxf(fmaf(acc[0][1][nn], scq[1], shq[1]), 0.f);
        rq.z = fmaxf(fmaf(acc[0][2][nn], scq[2], shq[2]), 0.f);
        rq.w = fmaxf(fmaf(acc[0][3][nn], scq[3], shq[3]), 0.f);
        *reinterpret_cast<float4*>(qo + (pidx << 6) + to * 4) = rq;
        // kv packed: hi16 = k, lo16 = v (keep DEFAULT caching: reused by K2)
        u32x4 pk;
        #pragma unroll
        for (int oi = 0; oi < 4; ++oi) {
            float rk = fmaxf(fmaf(acc[1][oi][nn], sck[oi], shk[oi]), 0.f);
            float rv = fmaxf(fmaf(acc[2][oi][nn], scv[oi], shv[oi]), 0.f);
            pk[oi] = (bf16_rtne(rk) << 16) | bf16_rtne(rv);
        }
        *reinterpret_cast<u32x4*>(kvo + (pidx << 6) + to * 4) = pk;
    }
}

// ---------------------------------------------------------------------------
// K2: gather + attention + weighted sum. One wave per point, lane = channel.
// Neighbor-index row is WAVE-UNIFORM: force it through the scalar path
// (readfirstlane -> s_load) so each gather is global_load_dword with an SGPR
// base + one shared lane*4 offset. No ds_bpermute, no per-gather VGPR math.
// x_info (268 MB, zero reuse) loaded NON-TEMPORAL. Writes feat over q IN PLACE.
// grid = B*N/4 blocks of 256 threads (4 waves = 4 points per block).
// ---------------------------------------------------------------------------
__global__ __launch_bounds__(256) void k_attn(
    const float*    __restrict__ xinfo,
    const int*      __restrict__ nidx,
    float*                       qfeat,   // q in, feat out (aliased on purpose)
    const uint32_t* __restrict__ kv)
{
    __shared__ float xs[64][68];   // [c][pl*16+j], pad 4 -> <=2-way bank alias
    const int tid  = threadIdx.x;
    const int lane = tid & 63;
    const int wv   = tid >> 6;
    const int p0   = blockIdx.x * 4;
    const int b    = p0 >> 14;
    const int n0   = p0 & 16383;
    const int p    = p0 + wv;

    // ---- neighbor indices via SCALAR path (p is wave-uniform) ----
    const int pu = __builtin_amdgcn_readfirstlane(p);
    const int4* irow = reinterpret_cast<const int4*>(nidx + ((size_t)pu << 4));
    int4 i0 = irow[0], i1 = irow[1], i2 = irow[2], i3 = irow[3];
    const int idxs[16] = {i0.x, i0.y, i0.z, i0.w,  i1.x, i1.y, i1.z, i1.w,
                          i2.x, i2.y, i2.z, i2.w,  i3.x, i3.y, i3.z, i3.w};

    // ---- gathers first: 16 independent loads, SGPR base + lane*4 ----
    uint32_t gr[16];
    #pragma unroll
    for (int j = 0; j < 16; ++j)
        gr[j] = kv[(((size_t)((b << 14) | idxs[j])) << 6) + lane];

    float qc = __builtin_nontemporal_load(qfeat + ((size_t)p << 6) + lane);

    // ---- cooperative x_info tile load (nt): 4096 floats = 4 x f32x4/thread ----
    const float* xbase = xinfo + (((size_t)b * 64) * NPT + n0) * 16;
    f32x4 xr[4];
    #pragma unroll
    for (int i = 0; i < 4; ++i) {
        int f = tid + i * 256;        // float4 index in tile, 0..1023
        int c = f >> 4, s = f & 15;   // channel, 16B-segment within 256B run
        xr[i] = __builtin_nontemporal_load(
            reinterpret_cast<const f32x4*>(xbase + (size_t)c * (NPT * 16) + s * 4));
    }
    #pragma unroll
    for (int i = 0; i < 4; ++i) {
        int f = tid + i * 256;
        int c = f >> 4, s = f & 15;
        *reinterpret_cast<f32x4*>(&xs[c][s * 4]) = xr[i];
    }

    // unpack gathers while LDS writes drain
    float kgv[16], vgv[16];
    #pragma unroll
    for (int j = 0; j < 16; ++j) {
        kgv[j] = __builtin_bit_cast(float, gr[j] & 0xFFFF0000u);
        vgv[j] = __builtin_bit_cast(float, gr[j] << 16);
    }
    __syncthreads();

    // ---- softmax over K=16, fully in-lane ----
    float w[16];
    #pragma unroll
    for (int k4 = 0; k4 < 4; ++k4) {
        float4 x4 = *reinterpret_cast<const float4*>(&xs[lane][wv * 16 + k4 * 4]);
        w[k4 * 4 + 0] = x4.x * (kgv[k4 * 4 + 0] - qc);
        w[k4 * 4 + 1] = x4.y * (kgv[k4 * 4 + 1] - qc);
        w[k4 * 4 + 2] = x4.z * (kgv[k4 * 4 + 2] - qc);
        w[k4 * 4 + 3] = x4.w * (kgv[k4 * 4 + 3] - qc);
    }

    float mx = w[0];
    #pragma unroll
    for (int j = 1; j < 16; ++j) mx = fmaxf(mx, w[j]);

    float es = 0.f, fsum = 0.f;
    #pragma unroll
    for (int j = 0; j < 16; ++j) {
        float e = __expf(w[j] - mx);
        es += e;
        fsum = fmaf(e, vgv[j], fsum);
    }

    qfeat[((size_t)p << 6) + lane] = fsum / es;   // feat, in place over q
}

// ---------------------------------------------------------------------------
// K3: mlp2 = 1x1 conv (O=128) + BN(eps=1e-6) + LeakyReLU(0.2).
// grid (N/64, B), block 256. Tile 128o x 64n; wt & feat transposed into LDS.
// Output [B][128][N]; float4 NT stores (256B per 16-lane segment).
// ---------------------------------------------------------------------------
__global__ __launch_bounds__(256) void k_mlp2(
    const float* __restrict__ feat,
    const float* __restrict__ m2w,
    const float* __restrict__ g2, const float* __restrict__ b2,
    const float* __restrict__ m2, const float* __restrict__ v2,
    float* __restrict__ out)
{
    __shared__ float wt [64][132];  // wt[c][o], padded (33 KiB)
    __shared__ float fsh[64][68];   // fsh[c][n], padded (17 KiB)
    const int tid = threadIdx.x;
    const int b   = blockIdx.y;
    const int n0  = blockIdx.x * 64;

    // ---- stage wt[c][o] from m2w[o][c] ----
    {
        const int o  = tid >> 1;          // 0..127
        const int ch = (tid & 1) * 32;    // 0 or 32
        const float4* src = reinterpret_cast<const float4*>(m2w + o * 64 + ch);
        #pragma unroll
        for (int k4 = 0; k4 < 8; ++k4) {
            float4 w4 = src[k4];
            wt[ch + k4 * 4 + 0][o] = w4.x;
            wt[ch + k4 * 4 + 1][o] = w4.y;
            wt[ch + k4 * 4 + 2][o] = w4.z;
            wt[ch + k4 * 4 + 3][o] = w4.w;
        }
    }
    // ---- stage fsh[c][n] from feat[b][n0+n][c] ----
    {
        const int c4 = tid & 15;       // float4 index along c
        const int nl = tid >> 4;       // 0..15
        #pragma unroll
        for (int i = 0; i < 4; ++i) {
            int n = nl + i * 16;
            float4 f4 = *reinterpret_cast<const float4*>(
                feat + (((size_t)b * NPT + n0 + n) << 6) + c4 * 4);
            fsh[c4 * 4 + 0][n] = f4.x;
            fsh[c4 * 4 + 1][n] = f4.y;
            fsh[c4 * 4 + 2][n] = f4.z;
            fsh[c4 * 4 + 3][n] = f4.w;
        }
    }
    __syncthreads();

    const int tn = tid & 15;   // lane's n-quad: n = tn*4 .. tn*4+3 (float4 stores)
    const int to = tid >> 4;   // 0..15 -> o quads {to*4..+3} and {64+to*4..+3}
    float acc[2][4][4];        // [half][oi][ni]
    #pragma unroll
    for (int h = 0; h < 2; ++h)
        #pragma unroll
        for (int i = 0; i < 4; ++i)
            #pragma unroll
            for (int j = 0; j < 4; ++j) acc[h][i][j] = 0.f;

    #pragma unroll 4
    for (int c = 0; c < 64; ++c) {
        float4 wa = *reinterpret_cast<const float4*>(&wt[c][to * 4]);
        float4 wb = *reinterpret_cast<const float4*>(&wt[c][64 + to * 4]);
        float4 f4 = *reinterpret_cast<const float4*>(&fsh[c][tn * 4]);
        float wra[4] = {wa.x, wa.y, wa.z, wa.w};
        float wrb[4] = {wb.x, wb.y, wb.z, wb.w};
        float fr[4]  = {f4.x, f4.y, f4.z, f4.w};
        #pragma unroll
        for (int oi = 0; oi < 4; ++oi)
            #pragma unroll
            for (int ni = 0; ni < 4; ++ni) {
                acc[0][oi][ni] = fmaf(wra[oi], fr[ni], acc[0][oi][ni]);
                acc[1][oi][ni] = fmaf(wrb[oi], fr[ni], acc[1][oi][ni]);
            }
    }

    #pragma unroll
    for (int h = 0; h < 2; ++h)
        #pragma unroll
        for (int oi = 0; oi < 4; ++oi) {
            int o = h * 64 + to * 4 + oi;
            float s  = g2[o] * rsqrtf(v2[o] + 1e-6f);
            float sh = b2[o] - m2[o] * s;
            f32x4 r;
            #pragma unroll
            for (int ni = 0; ni < 4; ++ni) {
                float y = fmaf(acc[h][oi][ni], s, sh);
                r[ni] = (y >= 0.f) ? y : 0.2f * y;
            }
            __builtin_nontemporal_store(r, reinterpret_cast<f32x4*>(
                out + (((size_t)b << 7) + o) * NPT + n0 + tn * 4));
        }
}

// ---------------------------------------------------------------------------
extern "C" void kernel_launch(void* const* d_in, const int* in_sizes, int n_in,
                              void* d_out, int out_size, void* d_ws, size_t ws_size,
                              hipStream_t stream)
{
    const float* xinfo   = (const float*)d_in[0];
    const float* feature = (const float*)d_in[1];
    const int*   nidx    = (const int*)  d_in[2];
    const float* Wq = (const float*)d_in[3];
    const float* Qg = (const float*)d_in[4];
    const float* Qb = (const float*)d_in[5];
    const float* Qm = (const float*)d_in[6];
    const float* Qv = (const float*)d_in[7];
    const float* Wk = (const float*)d_in[8];
    const float* Kg = (const float*)d_in[9];
    const float* Kb = (const float*)d_in[10];
    const float* Km = (const float*)d_in[11];
    const float* Kv = (const float*)d_in[12];
    const float* Wv = (const float*)d_in[13];
    const float* Vg = (const float*)d_in[14];
    const float* Vb = (const float*)d_in[15];
    const float* Vm = (const float*)d_in[16];
    const float* Vv = (const float*)d_in[17];
    const float* m2w = (const float*)d_in[18];
    const float* g2  = (const float*)d_in[19];
    const float* b2  = (const float*)d_in[20];
    const float* m2  = (const float*)d_in[21];
    const float* v2  = (const float*)d_in[22];
    float* out = (float*)d_out;

    // workspace: q/feat (in-place) 16 MiB fp32, packed kv 16 MiB u32
    float*    ws    = (float*)d_ws;
    float*    qf    = ws;
    uint32_t* kvbuf = (uint32_t*)(ws + (size_t)NB * NPT * 64);

    k_qkv<<<dim3(NPT / 64, NB), 256, 0, stream>>>(
        feature, Wq, Wk, Wv,
        Qg, Qb, Qm, Qv, Kg, Kb, Km, Kv, Vg, Vb, Vm, Vv,
        qf, kvbuf);

    k_attn<<<(NB * NPT) / 4, 256, 0, stream>>>(xinfo, nidx, qf, kvbuf);

    k_mlp2<<<dim3(NPT / 64, NB), 256, 0, stream>>>(qf, m2w, g2, b2, m2, v2, out);
}